// Round 8
// baseline (224.824 us; speedup 1.0000x reference)
//
#include <hip/hip_runtime.h>
#include <math.h>

#define TT 256
#define HIDDEN 2048
#define NH 16
#define HD 128
#define KDIM 2048
#define NCG 30

typedef _Float16 h4 __attribute__((ext_vector_type(4)));
typedef _Float16 half8 __attribute__((ext_vector_type(8)));
typedef float floatx4 __attribute__((ext_vector_type(4)));

__device__ __forceinline__ half8 cvt8(const float4 x, const float4 y) {
    half8 f;
    f[0] = (_Float16)x.x; f[1] = (_Float16)x.y; f[2] = (_Float16)x.z; f[3] = (_Float16)x.w;
    f[4] = (_Float16)y.x; f[5] = (_Float16)y.y; f[6] = (_Float16)y.z; f[7] = (_Float16)y.w;
    return f;
}

// async 16B/lane global->LDS (dest = wave-uniform base + lane*16)
__device__ __forceinline__ void glds16(const void* g, void* l) {
    __builtin_amdgcn_global_load_lds(
        (const __attribute__((address_space(1))) void*)g,
        (__attribute__((address_space(3))) void*)l, 16, 0, 0);
}

// ============ f16-MFMA GEMM: 32x128 tile, BK=64, dbuf LDS ============
// Weights read ONCE from f32 (no wtrans): B-tile DMA'd raw-f32 into linear
// LDS [64k][128n] via glds16 (1KB/wave-instr, async, no reg traffic). The
// k-contiguous MFMA fragment is built on the READ side: 8 x ds_read_b32 down
// a column + cvt8. Known cost: 4-way bank alias on those reads (row stride
// 128 words == 0 mod 32; quads collide) = 1.58x on ~190cy -> acceptable vs
// the 2000cy/step exposed-latency of reg-staged scalar loads (round-7 miss).
// nt==48 = fused ab tile (Wa/Wb reg-staged f32 to cols 0-31, 32-127 zeroed;
// wave-0 epilogue applies logsigmoid/sigmoid -> g/beta).
#define ASTR 72   // halves per A row (64 + 8 pad)
#define GEMM_LDS (2 * 64 * 128 * 4 + 2 * 32 * ASTR * 2)   // 65536 + 9216 = 74752

__global__ __launch_bounds__(256) void gemm_kernel(
    const float* __restrict__ A,
    const float* __restrict__ Wq, const float* __restrict__ Wk,
    const float* __restrict__ Wv,
    const float* __restrict__ Wa, const float* __restrict__ Wb,
    float* __restrict__ C0, float* __restrict__ C1, float* __restrict__ C2,
    const float* __restrict__ ba, const float* __restrict__ bb,
    float* __restrict__ g, float* __restrict__ beta)
{
    extern __shared__ char smem[];
    float* Bf = (float*)smem;                            // [2][64][128] f32
    _Float16* Ash = (_Float16*)(smem + 65536);           // [2][32*ASTR]

    const int tid = threadIdx.x, lane = tid & 63, w = tid >> 6;
    const int q = lane >> 4, l16 = lane & 15;

    const int b = blockIdx.x;
    const int xcd = b & 7, gslot = b >> 3;
    int nt, mt;
    if (gslot < 48) { nt = xcd * 6 + (gslot >> 3); mt = gslot & 7; }
    else           { nt = 48;                      mt = xcd; }
    const int mat = nt >> 4;              // 0..2 weights, 3 = ab tile
    const int ntile = nt & 15;
    const int n0 = ntile * 128;
    const float* __restrict__ W = (mat == 0) ? Wq : (mat == 1) ? Wk : (mat == 2) ? Wv : Wa;
    float* __restrict__ C = (mat == 0) ? C0 : (mat == 1) ? C1 : C2;
    const int m0 = mt * 32;

    const int ar = tid >> 3, ac = (tid & 7) * 8;
    const float* __restrict__ Ap = &A[(size_t)(m0 + ar) * KDIM + ac];

    floatx4 acc[2][2] = {};
    float4 ax, ay;
    float bab[16];      // mat==3: two k-octets at h = lane&15

    // DMA B(s) into buffer buf: 8 instr/wave, each covers 2 rows (1024B)
    auto stageB = [&](int s, int buf) {
#pragma unroll
        for (int i = 0; i < 8; i++) {
            const int r0 = w * 16 + i * 2;               // wave-uniform
            const int row = r0 + (lane >> 5);
            glds16(&W[(size_t)(s * 64 + row) * KDIM + n0 + (lane & 31) * 4],
                   &Bf[(buf * 64 + r0) * 128]);
        }
    };
    auto loadBab = [&](int s) {
        if (w >= 2) return;
        const float* __restrict__ Wsrc = (w == 0) ? Wa : Wb;
        const int hh = lane & 15, ko = lane >> 4;
#pragma unroll
        for (int hf = 0; hf < 2; hf++)
#pragma unroll
            for (int j = 0; j < 8; j++)
                bab[hf * 8 + j] = Wsrc[(size_t)(s * 64 + hf * 32 + ko * 8 + j) * NH + hh];
    };
    auto writeBab = [&](int buf) {
        if (w >= 2) return;
        const int hh = lane & 15, ko = lane >> 4;
        const int col = w * 16 + hh;                     // Wa cols 0-15, Wb 16-31
#pragma unroll
        for (int hf = 0; hf < 2; hf++)
#pragma unroll
            for (int j = 0; j < 8; j++)
                Bf[(buf * 64 + hf * 32 + ko * 8 + j) * 128 + col] = bab[hf * 8 + j];
    };

    // ---- prologue ----
    if (mat == 3) {
        // zero cols 32..127 of both buffers once (never rewritten)
        for (int i = tid; i < 2 * 64 * 96; i += 256) {
            const int buf = i / 6144;
            const int rest = i - buf * 6144;
            const int row = rest / 96, col = 32 + (rest - row * 96);
            Bf[(buf * 64 + row) * 128 + col] = 0.f;
        }
        loadBab(0); writeBab(0); loadBab(1);
    } else {
        stageB(0, 0);
    }
    ax = *(const float4*)&Ap[0]; ay = *(const float4*)&Ap[4];
    *(half8*)&Ash[ar * ASTR + ac] = cvt8(ax, ay);
    ax = *(const float4*)&Ap[64]; ay = *(const float4*)&Ap[68];
    __syncthreads();   // drains B-DMA(0); Ash[0] visible

    const int NSTEP = KDIM / 64;   // 32
    for (int s = 0; s < NSTEP; s++) {
        const int cur = s & 1;
        if (mat != 3 && s + 1 < NSTEP)
            stageB(s + 1, cur ^ 1);    // in flight during compute; buf cur^1 free since barrier(s-1)
#pragma unroll
        for (int kk = 0; kk < 2; kk++) {
            float f0[8], f1[8];
#pragma unroll
            for (int j = 0; j < 8; j++) {
                const int rowb = (cur * 64 + kk * 32 + q * 8 + j) * 128 + w * 32 + l16;
                f0[j] = Bf[rowb];
                f1[j] = Bf[rowb + 16];
            }
            const half8 bf0 = cvt8(*(const float4*)&f0[0], *(const float4*)&f0[4]);
            const half8 bf1 = cvt8(*(const float4*)&f1[0], *(const float4*)&f1[4]);
            const half8 af0 = *(const half8*)&Ash[cur * 32 * ASTR + l16 * ASTR + kk * 32 + q * 8];
            const half8 af1 = *(const half8*)&Ash[cur * 32 * ASTR + (16 + l16) * ASTR + kk * 32 + q * 8];
            acc[0][0] = __builtin_amdgcn_mfma_f32_16x16x32_f16(af0, bf0, acc[0][0], 0, 0, 0);
            acc[0][1] = __builtin_amdgcn_mfma_f32_16x16x32_f16(af0, bf1, acc[0][1], 0, 0, 0);
            acc[1][0] = __builtin_amdgcn_mfma_f32_16x16x32_f16(af1, bf0, acc[1][0], 0, 0, 0);
            acc[1][1] = __builtin_amdgcn_mfma_f32_16x16x32_f16(af1, bf1, acc[1][1], 0, 0, 0);
        }
        if (s + 1 < NSTEP) {
            if (mat == 3) {
                writeBab(cur ^ 1);
                if (s + 2 < NSTEP) loadBab(s + 2);
            }
            *(half8*)&Ash[(cur ^ 1) * 32 * ASTR + ar * ASTR + ac] = cvt8(ax, ay);
            if (s + 2 < NSTEP) {
                ax = *(const float4*)&Ap[(s + 2) * 64];
                ay = *(const float4*)&Ap[(s + 2) * 64 + 4];
            }
        }
        __syncthreads();   // drains B-DMA(s+1), Ash(s+1) visible, guards buffer reuse
    }

    if (mat == 3) {
        if (w == 0) {
            const float bav = ba[l16], bbv = bb[l16];
#pragma unroll
            for (int r = 0; r < 4; r++) {
                const int t0r = m0 + q * 4 + r, t1r = m0 + 16 + q * 4 + r;
                float z0 = acc[0][0][r] + bav;
                g[t0r * NH + l16] = fminf(z0, 0.f) - log1pf(__expf(-fabsf(z0)));
                float z1 = acc[0][1][r] + bbv;
                beta[t0r * NH + l16] = 1.f / (1.f + __expf(-z1));
                float z2 = acc[1][0][r] + bav;
                g[t1r * NH + l16] = fminf(z2, 0.f) - log1pf(__expf(-fabsf(z2)));
                float z3 = acc[1][1][r] + bbv;
                beta[t1r * NH + l16] = 1.f / (1.f + __expf(-z3));
            }
        }
        return;
    }

#pragma unroll
    for (int r = 0; r < 4; r++) {
        C[(size_t)(m0 + q * 4 + r) * KDIM + n0 + w * 32 + l16] = acc[0][0][r];
        C[(size_t)(m0 + q * 4 + r) * KDIM + n0 + w * 32 + 16 + l16] = acc[0][1][r];
        C[(size_t)(m0 + 16 + q * 4 + r) * KDIM + n0 + w * 32 + l16] = acc[1][0][r];
        C[(size_t)(m0 + 16 + q * 4 + r) * KDIM + n0 + w * 32 + 16 + l16] = acc[1][1][r];
    }
}

// ============ 32x64-tile output GEMM, Wo f32 DMA + LDS-read transpose ============
// 32 nt x 8 mt = 256 blocks -> 1 block/CU.
__global__ __launch_bounds__(256) void gemm64_kernel(
    const float* __restrict__ A, const float* __restrict__ Wo,
    float* __restrict__ C)
{
    __shared__ __align__(16) float Bf[2][64][64];            // 32 KB
    __shared__ __align__(16) _Float16 Ash[2][32 * ASTR];     // 9 KB

    const int tid = threadIdx.x, lane = tid & 63, w = tid >> 6;
    const int q = lane >> 4, l16 = lane & 15;
    const int b = blockIdx.x;
    const int xcd = b & 7, gslot = b >> 3;
    const int nt = xcd * 4 + (gslot >> 3), mt = gslot & 7;
    const int n0 = nt * 64, m0 = mt * 32;

    const int ar = tid >> 3, ac = (tid & 7) * 8;
    const float* __restrict__ Ap = &A[(size_t)(m0 + ar) * KDIM + ac];

    floatx4 acc0 = {}, acc1 = {};
    float4 ax, ay;

    // DMA B(s): 4 instr/wave, each covers 4 rows (1024B)
    auto stageB = [&](int s, int buf) {
#pragma unroll
        for (int i = 0; i < 4; i++) {
            const int r0 = w * 16 + i * 4;               // wave-uniform
            const int row = r0 + (lane >> 4);
            glds16(&Wo[(size_t)(s * 64 + row) * KDIM + n0 + (lane & 15) * 4],
                   &Bf[buf][r0][0]);
        }
    };

    stageB(0, 0);
    ax = *(const float4*)&Ap[0]; ay = *(const float4*)&Ap[4];
    *(half8*)&Ash[0][ar * ASTR + ac] = cvt8(ax, ay);
    ax = *(const float4*)&Ap[64]; ay = *(const float4*)&Ap[68];
    __syncthreads();

    const int NSTEP = KDIM / 64;   // 32
    for (int s = 0; s < NSTEP; s++) {
        const int cur = s & 1;
        if (s + 1 < NSTEP) stageB(s + 1, cur ^ 1);
#pragma unroll
        for (int kk = 0; kk < 2; kk++) {
            float f[8];
#pragma unroll
            for (int j = 0; j < 8; j++)
                f[j] = Bf[cur][kk * 32 + q * 8 + j][w * 16 + l16];
            const half8 bf  = cvt8(*(const float4*)&f[0], *(const float4*)&f[4]);
            const half8 af0 = *(const half8*)&Ash[cur][l16 * ASTR + kk * 32 + q * 8];
            const half8 af1 = *(const half8*)&Ash[cur][(16 + l16) * ASTR + kk * 32 + q * 8];
            acc0 = __builtin_amdgcn_mfma_f32_16x16x32_f16(af0, bf, acc0, 0, 0, 0);
            acc1 = __builtin_amdgcn_mfma_f32_16x16x32_f16(af1, bf, acc1, 0, 0, 0);
        }
        if (s + 1 < NSTEP) {
            *(half8*)&Ash[cur ^ 1][ar * ASTR + ac] = cvt8(ax, ay);
            if (s + 2 < NSTEP) {
                ax = *(const float4*)&Ap[(s + 2) * 64];
                ay = *(const float4*)&Ap[(s + 2) * 64 + 4];
            }
        }
        __syncthreads();
    }

#pragma unroll
    for (int r = 0; r < 4; r++) {
        C[(size_t)(m0 + q * 4 + r) * KDIM + n0 + w * 16 + l16] = acc0[r];
        C[(size_t)(m0 + 16 + q * 4 + r) * KDIM + n0 + w * 16 + l16] = acc1[r];
    }
}

// ---------------- conv(4)+silu+l2norm, q&k fused per (t,h) ----------------
__global__ __launch_bounds__(256) void conv_silu_l2_kernel(
    const float* __restrict__ q_pre, const float* __restrict__ k_pre,
    const float* __restrict__ cwq, const float* __restrict__ cwk,
    float* __restrict__ qn, float* __restrict__ kn)
{
    const int t = blockIdx.x, h = blockIdx.y;
    const int which = threadIdx.x >> 7, d = threadIdx.x & 127;
    const int w = threadIdx.x >> 6;
    const int c = h * HD + d;
    const float* pre = which ? k_pre : q_pre;
    const float* cw  = which ? cwk : cwq;
    float y = 0.f;
#pragma unroll
    for (int i = 0; i < 4; i++) {
        const int ts = t - 3 + i;
        if (ts >= 0) y = fmaf(pre[ts * KDIM + c], cw[c * 4 + i], y);
    }
    const float s = y / (1.f + __expf(-y));
    float v = s * s;
#pragma unroll
    for (int off = 32; off > 0; off >>= 1) v += __shfl_down(v, off, 64);
    __shared__ float red[4];
    if ((threadIdx.x & 63) == 0) red[w] = v;
    __syncthreads();
    const float sum = red[which * 2] + red[which * 2 + 1];
    float* dst = which ? kn : qn;
    dst[t * KDIM + c] = s * rsqrtf(sum + 1e-6f);
}

// ================= MFMA-batched mesa CG + fused rmsnorm =================
// 16-row t-tiles, grid = 256 = 1 block/CU: kernel time = slowest block's serial
// CG chain. Latency cuts (VGPRs are free at 1 wave/SIMD):
//  - phase-2 Kt A-frags hoisted to registers (loop-invariant)
//  - V epilogue B-frags preloaded before the CG loop
//  - 2-way split MFMA accumulator chains in both phases
//  - G prefix-scan + lamb softplus computed in-block
// Scalar chain kept EXACT (two explicit shfl-reduce chains): analytic-rsn
// fusion cancels catastrophically -> f16 overflow -> NaN (round-2 failure).
#define PSTR 136
#define YSTR 264

template<int SMAX>
__device__ __forceinline__ void mesa_cg(
    const float* __restrict__ qn, const float* __restrict__ kn, const float* __restrict__ vv,
    const float* __restrict__ g, const float* __restrict__ bet, const float* __restrict__ lp,
    const float* __restrict__ onw, float* __restrict__ out,
    int h, int t0, _Float16* Psh, _Float16* Ysh, float* red,
    float* Gsh, float* bets)
{
    constexpr int NSUB1 = SMAX / 64;
    constexpr int NK2   = SMAX / 32;

    const int tid = threadIdx.x, lane = tid & 63, w = tid >> 6;
    const int quad = lane >> 4, l16 = lane & 15;
    const int tmy = t0 + l16;
    const int dbase = w * 32;

    // ---- in-block G prefix scan over t=0..255 (this head) + beta staging ----
    {
        float sc = g[tid * NH + h];
#pragma unroll
        for (int off = 1; off < 64; off <<= 1) {
            const float o = __shfl_up(sc, off, 64);
            if (lane >= off) sc += o;
        }
        if (lane == 63) red[w] = sc;
        bets[tid] = bet[tid * NH + h];
        __syncthreads();
        float woff = 0.f;
        for (int u = 0; u < w; u++) woff += red[u];
        Gsh[tid] = sc + woff;
        __syncthreads();
    }

    // phase-1 A-frags: K rows (s-major), per-wave s-slice, held in regs
    half8 K1[NSUB1][4];
#pragma unroll
    for (int ii = 0; ii < NSUB1; ii++) {
        const int srow = 16 * (w + 4 * ii) + l16;
        const float* kp = &kn[(srow * NH + h) * HD];
#pragma unroll
        for (int kk = 0; kk < 4; kk++) {
            const float4 a = *(const float4*)&kp[kk * 32 + quad * 8];
            const float4 b = *(const float4*)&kp[kk * 32 + quad * 8 + 4];
            K1[ii][kk] = cvt8(a, b);
        }
    }

    // phase-2 A-frags: K^T (d-major), loop-invariant -> registers.
    half8 KtF[2][NK2];
#pragma unroll
    for (int ss = 0; ss < 2; ss++) {
        const int d = dbase + ss * 16 + l16;
#pragma unroll
        for (int kk = 0; kk < NK2; kk++) {
#pragma unroll
            for (int j = 0; j < 8; j++) {
                const int s = kk * 32 + quad * 8 + j;
                KtF[ss][kk][j] = (_Float16)kn[(s * NH + h) * HD + d];
            }
        }
    }

    // epilogue V B-frags: independent of CG loop -> preload
    half8 Vf[NK2][2];
#pragma unroll
    for (int kk = 0; kk < NK2; kk++) {
#pragma unroll
        for (int ss = 0; ss < 2; ss++) {
            const int dv = dbase + ss * 16 + l16;
#pragma unroll
            for (int j = 0; j < 8; j++) {
                const int s = kk * 32 + quad * 8 + j;
                Vf[kk][ss][j] = (_Float16)vv[(s * NH + h) * HD + dv];
            }
        }
    }

    const float Gt = Gsh[tmy];
    float Wm[NSUB1][4];
#pragma unroll
    for (int ii = 0; ii < NSUB1; ii++)
#pragma unroll
        for (int r = 0; r < 4; r++) {
            const int s = 16 * (w + 4 * ii) + quad * 4 + r;
            Wm[ii][r] = (s <= tmy) ? bets[s] * __expf(Gt - Gsh[s]) : 0.f;
        }
    float lam[8], xv[8], rv[8], pv[8];
#pragma unroll
    for (int ss = 0; ss < 2; ss++)
#pragma unroll
        for (int r = 0; r < 4; r++) {
            const int e = ss * 4 + r;
            const int d = dbase + ss * 16 + quad * 4 + r;
            const float lx = lp[h * HD + d];
            lam[e] = fmaxf(lx, 0.f) + log1pf(__expf(-fabsf(lx))) + 0.25f;
            const float b = qn[(tmy * NH + h) * HD + d];
            xv[e] = 0.f; rv[e] = b; pv[e] = b;
        }
    float rs = 0.f;
#pragma unroll
    for (int e = 0; e < 8; e++) rs += rv[e] * rv[e];
    rs += __shfl_xor(rs, 16, 64); rs += __shfl_xor(rs, 32, 64);

    auto writeP = [&](const float* src) {
#pragma unroll
        for (int ss = 0; ss < 2; ss++) {
            h4 ph;
            ph.x = (_Float16)src[ss * 4 + 0]; ph.y = (_Float16)src[ss * 4 + 1];
            ph.z = (_Float16)src[ss * 4 + 2]; ph.w = (_Float16)src[ss * 4 + 3];
            *(h4*)&Psh[l16 * PSTR + dbase + ss * 16 + quad * 4] = ph;
        }
    };
    writeP(pv);

    for (int it = 0; it <= NCG; it++) {
        __syncthreads();
        // ---- phase 1: Y = Wm .* (K P), 2-way split acc chains ----
        floatx4 acc1a[NSUB1] = {}, acc1b[NSUB1] = {};
#pragma unroll
        for (int kk = 0; kk < 2; kk++) {
            const half8 bfa = *(const half8*)&Psh[l16 * PSTR + kk * 32 + quad * 8];
            const half8 bfb = *(const half8*)&Psh[l16 * PSTR + (kk + 2) * 32 + quad * 8];
#pragma unroll
            for (int ii = 0; ii < NSUB1; ii++) {
                acc1a[ii] = __builtin_amdgcn_mfma_f32_16x16x32_f16(K1[ii][kk], bfa, acc1a[ii], 0, 0, 0);
                acc1b[ii] = __builtin_amdgcn_mfma_f32_16x16x32_f16(K1[ii][kk + 2], bfb, acc1b[ii], 0, 0, 0);
            }
        }
#pragma unroll
        for (int ii = 0; ii < NSUB1; ii++) {
            h4 yh;
            yh.x = (_Float16)(Wm[ii][0] * (acc1a[ii][0] + acc1b[ii][0]));
            yh.y = (_Float16)(Wm[ii][1] * (acc1a[ii][1] + acc1b[ii][1]));
            yh.z = (_Float16)(Wm[ii][2] * (acc1a[ii][2] + acc1b[ii][2]));
            yh.w = (_Float16)(Wm[ii][3] * (acc1a[ii][3] + acc1b[ii][3]));
            *(h4*)&Ysh[l16 * YSTR + 16 * (w + 4 * ii) + quad * 4] = yh;
        }
        __syncthreads();
        if (it == NCG) break;

        // ---- phase 2: Ap = K^T Y + lam.*p, A-frags from regs, 2-way split ----
        floatx4 acc2a[2] = {}, acc2b[2] = {};
#pragma unroll
        for (int kk = 0; kk < NK2; kk += 2) {
            const half8 bf0 = *(const half8*)&Ysh[l16 * YSTR + kk * 32 + quad * 8];
            const half8 bf1 = *(const half8*)&Ysh[l16 * YSTR + (kk + 1) * 32 + quad * 8];
#pragma unroll
            for (int ss = 0; ss < 2; ss++) {
                acc2a[ss] = __builtin_amdgcn_mfma_f32_16x16x32_f16(KtF[ss][kk], bf0, acc2a[ss], 0, 0, 0);
                acc2b[ss] = __builtin_amdgcn_mfma_f32_16x16x32_f16(KtF[ss][kk + 1], bf1, acc2b[ss], 0, 0, 0);
            }
        }
        // ---- scalar chain: exact CG (two explicit reduce chains) ----
        float Ap[8], pAp = 0.f;
#pragma unroll
        for (int ss = 0; ss < 2; ss++)
#pragma unroll
            for (int r = 0; r < 4; r++) {
                const int e = ss * 4 + r;
                Ap[e] = (acc2a[ss][r] + acc2b[ss][r]) + lam[e] * pv[e];
                pAp = fmaf(pv[e], Ap[e], pAp);
            }
        pAp += __shfl_xor(pAp, 16, 64); pAp += __shfl_xor(pAp, 32, 64);
        const float alpha = rs / (pAp + 1e-12f);
        float rsn = 0.f;
#pragma unroll
        for (int e = 0; e < 8; e++) {
            xv[e] = fmaf(alpha, pv[e], xv[e]);
            rv[e] = fmaf(-alpha, Ap[e], rv[e]);
            rsn = fmaf(rv[e], rv[e], rsn);
        }
        rsn += __shfl_xor(rsn, 16, 64); rsn += __shfl_xor(rsn, 32, 64);
        const float bcg = rsn / (rs + 1e-12f);
#pragma unroll
        for (int e = 0; e < 8; e++) pv[e] = fmaf(bcg, pv[e], rv[e]);
        rs = rsn;
        writeP(it == NCG - 1 ? xv : pv);
    }

    // ---- epilogue: O = Y^T V (V from preloaded regs), fused rmsnorm ----
    floatx4 accOa[2] = {}, accOb[2] = {};
#pragma unroll
    for (int kk = 0; kk < NK2; kk += 2) {
        const half8 af0 = *(const half8*)&Ysh[l16 * YSTR + kk * 32 + quad * 8];
        const half8 af1 = *(const half8*)&Ysh[l16 * YSTR + (kk + 1) * 32 + quad * 8];
#pragma unroll
        for (int ss = 0; ss < 2; ss++) {
            accOa[ss] = __builtin_amdgcn_mfma_f32_16x16x32_f16(af0, Vf[kk][ss], accOa[ss], 0, 0, 0);
            accOb[ss] = __builtin_amdgcn_mfma_f32_16x16x32_f16(af1, Vf[kk + 1][ss], accOb[ss], 0, 0, 0);
        }
    }
    float accO[2][4];
#pragma unroll
    for (int ss = 0; ss < 2; ss++)
#pragma unroll
        for (int r = 0; r < 4; r++) accO[ss][r] = accOa[ss][r] + accOb[ss][r];

    float part[4];
#pragma unroll
    for (int r = 0; r < 4; r++) {
        part[r] = accO[0][r] * accO[0][r] + accO[1][r] * accO[1][r];
#pragma unroll
        for (int off = 1; off < 16; off <<= 1) part[r] += __shfl_xor(part[r], off, 64);
    }
    if (l16 == 0) {
#pragma unroll
        for (int r = 0; r < 4; r++) red[w * 16 + quad * 4 + r] = part[r];
    }
    __syncthreads();
    const float w0 = onw[dbase + l16], w1 = onw[dbase + 16 + l16];
#pragma unroll
    for (int r = 0; r < 4; r++) {
        const int qr = quad * 4 + r;
        const float sumd = red[qr] + red[16 + qr] + red[32 + qr] + red[48 + qr];
        const float sc = rsqrtf(sumd * (1.f / HD) + 1e-5f);
        const int trow = ((t0 + qr) * NH + h) * HD;
        out[trow + dbase + l16] = accO[0][r] * sc * w0;
        out[trow + dbase + 16 + l16] = accO[1][r] * sc * w1;
    }
}

__global__ __launch_bounds__(256, 1) void mesa_kernel(
    const float* __restrict__ qn, const float* __restrict__ kn, const float* __restrict__ vv,
    const float* __restrict__ g, const float* __restrict__ bet, const float* __restrict__ lp,
    const float* __restrict__ onw, float* __restrict__ out)
{
    __shared__ __align__(16) _Float16 Psh[16 * PSTR];
    __shared__ __align__(16) _Float16 Ysh[16 * YSTR];
    __shared__ float red[64];
    __shared__ float Gsh[256];
    __shared__ float bets[256];
    const int h = blockIdx.x, jb = blockIdx.y, t0 = jb * 16;
    switch (jb >> 2) {
        case 0:  mesa_cg<64> (qn, kn, vv, g, bet, lp, onw, out, h, t0, Psh, Ysh, red, Gsh, bets); break;
        case 1:  mesa_cg<128>(qn, kn, vv, g, bet, lp, onw, out, h, t0, Psh, Ysh, red, Gsh, bets); break;
        case 2:  mesa_cg<192>(qn, kn, vv, g, bet, lp, onw, out, h, t0, Psh, Ysh, red, Gsh, bets); break;
        default: mesa_cg<256>(qn, kn, vv, g, bet, lp, onw, out, h, t0, Psh, Ysh, red, Gsh, bets); break;
    }
}

extern "C" void kernel_launch(void* const* d_in, const int* in_sizes, int n_in,
                              void* d_out, int out_size, void* d_ws, size_t ws_size,
                              hipStream_t stream)
{
    (void)in_sizes; (void)n_in; (void)out_size; (void)ws_size;
    const float* x   = (const float*)d_in[0];
    const float* Wq  = (const float*)d_in[1];
    const float* Wk  = (const float*)d_in[2];
    const float* Wv  = (const float*)d_in[3];
    const float* Wa  = (const float*)d_in[4];
    const float* ba  = (const float*)d_in[5];
    const float* Wb  = (const float*)d_in[6];
    const float* bb  = (const float*)d_in[7];
    const float* cwq = (const float*)d_in[8];
    const float* cwk = (const float*)d_in[9];
    const float* lp  = (const float*)d_in[10];
    const float* onw = (const float*)d_in[11];
    const float* Wo  = (const float*)d_in[12];

    char* wsb = (char*)d_ws;
    float* q_pre = (float*)wsb;
    float* k_pre = q_pre + 524288;
    float* v     = k_pre + 524288;
    float* qn    = v + 524288;
    float* kn    = qn + 524288;
    float* g     = kn + 524288;
    float* beta  = g + 4096;
    float* onorm = q_pre;
    float* outp  = (float*)d_out;

    (void)hipFuncSetAttribute((const void*)gemm_kernel,
                              hipFuncAttributeMaxDynamicSharedMemorySize, GEMM_LDS);
    gemm_kernel<<<dim3(392), 256, GEMM_LDS, stream>>>(x, Wq, Wk, Wv, Wa, Wb,
                                                      q_pre, k_pre, v, ba, bb, g, beta);
    conv_silu_l2_kernel<<<dim3(TT, NH), 256, 0, stream>>>(q_pre, k_pre, cwq, cwk, qn, kn);

    mesa_kernel<<<dim3(NH, 16), 256, 0, stream>>>(qn, kn, v, g, beta, lp, onw, onorm);

    gemm64_kernel<<<dim3(256), 256, 0, stream>>>(onorm, Wo, outp);
}